// Round 5
// baseline (455.976 us; speedup 1.0000x reference)
//
#include <hip/hip_runtime.h>
#include <hip/hip_bf16.h>

// ---------------------------------------------------------------------------
// HebbianNetwork: logits + 3 coactivation matrices.
//   B=8192, D_IN=1024, H1=H2=2048, N_CLS=1000
// Forward: bf16 MFMA (16x16x32). R9: 256^2 8-phase (751 TF). R12: per-phase
// WAITV pre-BAR (race-free, 937 TF, MfmaUtil 38%) — but reads and MFMA sit in
// disjoint barrier windows: LDS pipe (~2300 cyc/tile) serializes with MFMA
// (~2480 cyc/tile). R13: ONE barrier per window; each window reads the NEXT
// window's operand, counted lgkmcnt(own-reads) drains only the previous
// window's reads, MFMA overlaps the in-flight reads on the LDS pipe.
// Rotation q2',q3',q0,q1 | q2,q3,q0,q1; alo reg-double-buffered (aloA/aloB).
// Stage slots + WAITV counts identical to R12 (re-audited: WAR gap >= 2
// windows, RAW via pre-BAR WAITV).
// gemm3 (N=1024) stays on the 128^2 2-phase kernel.
// Coacts: int8 MFMA (16x16x64) 128x128 tile, BK=128, split-K, partial-store.
// ---------------------------------------------------------------------------

typedef short v8s __attribute__((ext_vector_type(8)));
typedef float v4f __attribute__((ext_vector_type(4)));
typedef int v4i __attribute__((ext_vector_type(4)));

enum { MODE_RELU = 0, MODE_LOGITS = 1 };

__device__ __forceinline__ void async_cp16(const void* gsrc, void* ldst) {
  __builtin_amdgcn_global_load_lds(
      (const __attribute__((address_space(1))) void*)gsrc,
      (__attribute__((address_space(3))) void*)ldst, 16, 0, 0);
}

#define FENCE asm volatile("" ::: "memory")
#define BAR()                         \
  do {                                \
    FENCE;                            \
    __builtin_amdgcn_s_barrier();     \
    FENCE;                            \
  } while (0)
#define WAITL()                                          \
  do {                                                   \
    asm volatile("s_waitcnt lgkmcnt(0)" ::: "memory");   \
    __builtin_amdgcn_sched_barrier(0);                   \
  } while (0)
#define WAITLN(n)                                           \
  do {                                                      \
    asm volatile("s_waitcnt lgkmcnt(" #n ")" ::: "memory"); \
    __builtin_amdgcn_sched_barrier(0);                      \
  } while (0)
#define WAITV(n)                                           \
  do {                                                     \
    asm volatile("s_waitcnt vmcnt(" #n ")" ::: "memory");  \
    __builtin_amdgcn_sched_barrier(0);                     \
  } while (0)
#define PRIO1 __builtin_amdgcn_s_setprio(1)
#define PRIO0 __builtin_amdgcn_s_setprio(0)

// ---------------- 256^2 single-barrier-window bf16 gemm -------------------
// C[M,N] = relu(A[M,K] @ B[N,K]^T + bias) -> bf16 Cout [M, ldc]
// Tout[col][row] = (z>0) int8, row stride 8192. Requires M%256==0, N%256==0,
// K%128==0, K>=256. Grid (N/256, M/256), 512 threads.
//
// 8 windows per iteration (tiles e=2i buf0, o=2i+1 buf1). Window:
//   [rd operand for NEXT window's MFMA (8|4 ds_read_b128)]
//   [stage 1 half-tile (2 global_load_lds)]
//   [lgkmcnt(N = this window's reads) -> drains PREVIOUS window's reads]
//   [16 MFMA on regs read LAST window  (overlaps this window's reads)]
//   [WAITV(k) validating NEXT window's pane]  [BAR]
//
// Windows (rd -> mma -> stage):
//  w0: rd aloA(e) | q2(o') = aloB*bhi | st pA1h<-Ahi(o)   | WAITV 6
//  w1: rd blo(e)  | q3(o') = ahi*bhi  | st pB1l<-Blo(o)   | WAITV 10
//  w2: rd ahi(e)  | q0(e)  = aloA*blo | st pB1h<-Bhi(o)   | WAITV 8
//  w3: rd bhi(e)  | q1(e)  = ahi*blo  | st pA0l<-Alo(e+2) | WAITV 8
//  w4: rd aloB(o) | q2(e)  = aloA*bhi | st pA0h<-Ahi(e+2) | WAITV 6
//  w5: rd blo(o)  | q3(e)  = ahi*bhi  | st pB0l<-Blo(e+2) | WAITV 10
//  w6: rd ahi(o)  | q0(o)  = aloB*blo | st pB0h<-Bhi(e+2) | WAITV 8
//  w7: rd bhi(o)  | q1(o)  = ahi*blo  | st pA1l<-Alo(o+2) | WAITV 8
// Reg liveness (audited): only alo needs 2 buffers (aloA even / aloB odd);
// every operand has >=1 full window between its read and use (covered by the
// next window's counted lgkm). DS returns are in-order per wave (all counted
// lgkm ops are ds_read_b128), so lgkmcnt(N) == "everything but my N newest".
// WAR: pane staged >= 2 windows after its last read window — all waves'
// reads of that pane were drained by their lgkm in the read window + 1,
// proven collective by that window's BAR, before the stage issues.
// RAW: WAITV(k) pre-BAR validates the pane the NEXT window reads (per-wave
// own-loads + barrier = collective; R12's proven discipline). k = 2 x
// (#halves staged after the target half): 6,10,8,8,6,10,8,8; prologue 8.
// Prologue stage order: Alo0,Ahi0,Blo0,Bhi0,Alo1 (matches steady counts).
// Final iter: stage sources clamped to tile 0 (landed, never read);
// tail: lgkm(0), q2(o_last), q3(o_last), WAITV(0), BAR, epilogue.
__global__ __launch_bounds__(512, 2) void gemm256_relu_wt(
    const __hip_bfloat16* __restrict__ A, const __hip_bfloat16* __restrict__ B,
    const float* __restrict__ bias, __hip_bfloat16* __restrict__ Cout,
    char* __restrict__ Tout, int K, int ldc) {
  __shared__ char smem[131072];
  const int t = threadIdx.x;
  const int m0 = blockIdx.y * 256;
  const int n0 = blockIdx.x * 256;

  // staging: half-tile = 128 rows x 64 cols bf16 = 1024 chunks(16B);
  // thread t owns chunks c0=t, c1=512+t. LDS dest linear (c*16), global
  // source granule XOR-swizzled: g = (c&7) ^ (row&7).
  const int c0 = t, c1 = 512 + t;
  const int r0s = c0 >> 3, r1s = c1 >> 3;
  const int goff0 = r0s * K + ((c0 & 7) ^ (r0s & 7)) * 8;
  const int goff1 = r1s * K + ((c1 & 7) ^ (r1s & 7)) * 8;
  const int loff0 = c0 * 16, loff1 = c1 * 16;

  const __hip_bfloat16* const Abase = A + (size_t)m0 * K;
  const __hip_bfloat16* const Bbase = B + (size_t)n0 * K;
  const size_t hk = (size_t)128 * K;  // element offset of rows 128..255

  // LDS panes (16KB each): [buf][A/B][lo/hi]
  char* const pA0l = smem;
  char* const pA0h = smem + 16384;
  char* const pB0l = smem + 32768;
  char* const pB0h = smem + 49152;
  char* const pA1l = smem + 65536;
  char* const pA1h = smem + 81920;
  char* const pB1l = smem + 98304;
  char* const pB1h = smem + 114688;

  const int lane = t & 63;
  const int wave = t >> 6;
  const int wm = wave >> 2;  // 0..1, M half (128 rows)
  const int wn = wave & 3;   // 0..3, N quarter (64 cols)
  const int lrow = lane & 15;
  const int quad = lane >> 4;
  // reader: content granule gk = ks*4+quad stored at slot gk ^ (row&7)
  const int sl0 = ((quad ^ (lrow & 7)) * 16);
  const int sl1 = (((quad + 4) ^ (lrow & 7)) * 16);
  const int ardA = (wm * 128 + lrow) * 128;  // byte, row stride 128B
  const int ardB = (wn * 64 + lrow) * 128;

  v4f acc[8][4] = {};
  v8s aloA[4][2], aloB[4][2], ahi[4][2], blo[2][2], bhi[2][2];

#define STAGE(dst, src)                                               \
  do {                                                                \
    async_cp16((const void*)((src) + goff0), (void*)((dst) + loff0)); \
    async_cp16((const void*)((src) + goff1), (void*)((dst) + loff1)); \
  } while (0)

#define LDA_H(dst, hh, bb)                                                   \
  _Pragma("unroll") for (int mi = 0; mi < 4; mi++) {                         \
    dst[mi][0] =                                                             \
        *(const v8s*)(smem + (bb) + ardA + (hh)*8192 + mi * 2048 + sl0);     \
    dst[mi][1] =                                                             \
        *(const v8s*)(smem + (bb) + ardA + (hh)*8192 + mi * 2048 + sl1);     \
  }

#define LDB_P(dst, pp, bb)                                                    \
  _Pragma("unroll") for (int ni = 0; ni < 2; ni++) {                          \
    dst[ni][0] = *(const v8s*)(smem + (bb) + 32768 + ardB +                   \
                               ((pp)*2 + ni) * 2048 + sl0);                   \
    dst[ni][1] = *(const v8s*)(smem + (bb) + 32768 + ardB +                   \
                               ((pp)*2 + ni) * 2048 + sl1);                   \
  }

#define MMA_Q(af, bf, MB, NB)                                               \
  _Pragma("unroll") for (int mi = 0; mi < 4; mi++)                          \
      _Pragma("unroll") for (int ni = 0; ni < 2; ni++)                      \
          _Pragma("unroll") for (int ks = 0; ks < 2; ks++)                  \
              acc[(MB) + mi][(NB) + ni] =                                   \
      __builtin_amdgcn_mfma_f32_16x16x32_bf16(                              \
          af[mi][ks], bf[ni][ks], acc[(MB) + mi][(NB) + ni], 0, 0, 0);

  // ---- prologue: Alo0, Ahi0, Blo0, Bhi0, Alo1 (order matters for vmcnt) --
  STAGE(pA0l, Abase);
  STAGE(pA0h, Abase + hk);
  STAGE(pB0l, Bbase);
  STAGE(pB0h, Bbase + hk);
  STAGE(pA1l, Abase + 64);
  WAITV(8);  // validates Alo0 (w0's pane) — pre-BAR, collective after BAR
  BAR();

  const int NI = K >> 7;  // iterations of 2 K-tiles
  const int NT = K >> 6;  // K-tiles

#pragma unroll 1
  for (int i = 0; i < NI; ++i) {
    const int to = 2 * i + 1;                         // always < NT
    const int t2 = (2 * i + 2 < NT) ? 2 * i + 2 : 0;  // clamped
    const int t3 = (2 * i + 3 < NT) ? 2 * i + 3 : 0;
    const __hip_bfloat16* Ao = Abase + to * 64;
    const __hip_bfloat16* Bo = Bbase + to * 64;
    const __hip_bfloat16* A2 = Abase + t2 * 64;
    const __hip_bfloat16* B2 = Bbase + t2 * 64;
    const __hip_bfloat16* A3 = Abase + t3 * 64;
    // w0: rd aloA(e) | st Ahi(o) | lgkm(8) | q2(o')
    LDA_H(aloA, 0, 0);
    STAGE(pA1h, Ao + hk);
    WAITLN(8);
    if (i) { PRIO1; MMA_Q(aloB, bhi, 0, 2); PRIO0; }
    WAITV(6);
    BAR();
    // w1: rd blo(e) | st Blo(o) | lgkm(4) | q3(o')
    LDB_P(blo, 0, 0);
    STAGE(pB1l, Bo);
    WAITLN(4);
    if (i) { PRIO1; MMA_Q(ahi, bhi, 4, 2); PRIO0; }
    WAITV(10);
    BAR();
    // w2: rd ahi(e) | st Bhi(o) | lgkm(8) | q0(e)
    LDA_H(ahi, 1, 0);
    STAGE(pB1h, Bo + hk);
    WAITLN(8);
    PRIO1; MMA_Q(aloA, blo, 0, 0); PRIO0;
    WAITV(8);
    BAR();
    // w3: rd bhi(e) | st Alo(e+2) | lgkm(4) | q1(e)
    LDB_P(bhi, 1, 0);
    STAGE(pA0l, A2);
    WAITLN(4);
    PRIO1; MMA_Q(ahi, blo, 4, 0); PRIO0;
    WAITV(8);
    BAR();
    // w4: rd aloB(o) | st Ahi(e+2) | lgkm(8) | q2(e)
    LDA_H(aloB, 0, 65536);
    STAGE(pA0h, A2 + hk);
    WAITLN(8);
    PRIO1; MMA_Q(aloA, bhi, 0, 2); PRIO0;
    WAITV(6);
    BAR();
    // w5: rd blo(o) | st Blo(e+2) | lgkm(4) | q3(e)
    LDB_P(blo, 0, 65536);
    STAGE(pB0l, B2);
    WAITLN(4);
    PRIO1; MMA_Q(ahi, bhi, 4, 2); PRIO0;
    WAITV(10);
    BAR();
    // w6: rd ahi(o) | st Bhi(e+2) | lgkm(8) | q0(o)
    LDA_H(ahi, 1, 65536);
    STAGE(pB0h, B2 + hk);
    WAITLN(8);
    PRIO1; MMA_Q(aloB, blo, 0, 0); PRIO0;
    WAITV(8);
    BAR();
    // w7: rd bhi(o) | st Alo(o+2) | lgkm(4) | q1(o)
    LDB_P(bhi, 1, 65536);
    STAGE(pA1l, A3);
    WAITLN(4);
    PRIO1; MMA_Q(ahi, blo, 4, 0); PRIO0;
    WAITV(8);
    BAR();
  }
  // tail: q2(o_last), q3(o_last) — drain w7's reads first
  WAITL();
  PRIO1; MMA_Q(aloB, bhi, 0, 2); PRIO0;
  PRIO1; MMA_Q(ahi, bhi, 4, 2); PRIO0;
  WAITV(0);  // drain clamped stage loads before LDS reuse (sT)
  BAR();
#undef STAGE
#undef LDA_H
#undef LDB_P
#undef MMA_Q

  // ---- epilogue ----
  float bv[4];
#pragma unroll
  for (int ni = 0; ni < 4; ni++) bv[ni] = bias[n0 + wn * 64 + ni * 16 + lrow];

  // C/D layout: col = lane&15, row = quad*4 + reg
#pragma unroll
  for (int mi = 0; mi < 8; mi++) {
    const int rowb = m0 + wm * 128 + mi * 16 + quad * 4;
#pragma unroll
    for (int ni = 0; ni < 4; ni++) {
      const int col = n0 + wn * 64 + ni * 16 + lrow;
#pragma unroll
      for (int r = 0; r < 4; r++) {
        const float v = acc[mi][ni][r] + bv[ni];
        Cout[(size_t)(rowb + r) * ldc + col] =
            __float2bfloat16(v > 0.f ? v : 0.f);
      }
    }
  }

  // fused binarized transpose: T[n0+c][m0+r] = (z > 0), via LDS 256x272
  char* const sT = smem;
#pragma unroll
  for (int ni = 0; ni < 4; ni++) {
    const int c = wn * 64 + ni * 16 + lrow;
#pragma unroll
    for (int mi = 0; mi < 8; mi++) {
      const int rw = wm * 128 + mi * 16 + quad * 4;
      char4 bits;
      bits.x = (acc[mi][ni][0] + bv[ni] > 0.f) ? 1 : 0;
      bits.y = (acc[mi][ni][1] + bv[ni] > 0.f) ? 1 : 0;
      bits.z = (acc[mi][ni][2] + bv[ni] > 0.f) ? 1 : 0;
      bits.w = (acc[mi][ni][3] + bv[ni] > 0.f) ? 1 : 0;
      *(char4*)&sT[c * 272 + rw] = bits;
    }
  }
  __syncthreads();
  const int rw2 = t >> 1;
  const int hf = (t & 1) * 128;
  char* dst = Tout + (size_t)(n0 + rw2) * 8192 + m0 + hf;
  const char* src = sT + rw2 * 272 + hf;
#pragma unroll
  for (int j = 0; j < 8; j++)
    *(int4*)(dst + j * 16) = *(const int4*)(src + j * 16);
}

// ---------------- bf16 forward gemm (BK=64, swizzled, 128^2) --------------
// Retained for gemm3 (N=1024: 256^2 grid would only be 128 blocks).
template <int MODE, int WT>
__global__ __launch_bounds__(256) void gemm_nt(
    const __hip_bfloat16* __restrict__ A, const __hip_bfloat16* __restrict__ B,
    const float* __restrict__ bias, void* __restrict__ Cout,
    char* __restrict__ Tout, int M, int N, int K, int n_store, int ldc) {
  __shared__ char smem[32768];
  __hip_bfloat16* sA = (__hip_bfloat16*)smem;           // 16KB
  __hip_bfloat16* sB = (__hip_bfloat16*)(smem + 16384); // 16KB
  const int t = threadIdx.x;
  const int m0 = blockIdx.y * 128;
  const int n0 = blockIdx.x * 128;

  const __hip_bfloat16* aG[4];
  const __hip_bfloat16* bG[4];
  char* lA[4];
  char* lB[4];
#pragma unroll
  for (int j = 0; j < 4; j++) {
    const int c = j * 256 + t;
    const int row = c >> 3;
    const int g = (c & 7) ^ (row & 7);
    aG[j] = A + (size_t)(m0 + row) * K + g * 8;
    bG[j] = B + (size_t)(n0 + row) * K + g * 8;
    lA[j] = (char*)sA + c * 16;
    lB[j] = (char*)sB + c * 16;
  }

  const int lane = t & 63;
  const int wave = t >> 6;
  const int wm = (wave & 1) * 64;
  const int wn = (wave >> 1) * 64;
  const int lrow = lane & 15;
  const int quad = lane >> 4;

  const int g0 = quad ^ (lrow & 7);
  const __hip_bfloat16* pa0 = sA + (wm + lrow) * 64 + g0 * 8;
  const __hip_bfloat16* pa1 = sA + (wm + lrow) * 64 + (g0 ^ 4) * 8;
  const __hip_bfloat16* pb0 = sB + (wn + lrow) * 64 + g0 * 8;
  const __hip_bfloat16* pb1 = sB + (wn + lrow) * 64 + (g0 ^ 4) * 8;

  v4f acc[4][4] = {};

  for (int k0 = 0; k0 < K; k0 += 64) {
#pragma unroll
    for (int j = 0; j < 4; j++) {
      async_cp16(aG[j] + k0, lA[j]);
      async_cp16(bG[j] + k0, lB[j]);
    }
    __syncthreads();

    v8s a0[4], b0[4], a1[4], b1[4];
#pragma unroll
    for (int i = 0; i < 4; i++) {
      a0[i] = *(const v8s*)(pa0 + i * 16 * 64);
      b0[i] = *(const v8s*)(pb0 + i * 16 * 64);
    }
#pragma unroll
    for (int mi = 0; mi < 4; mi++)
#pragma unroll
      for (int ni = 0; ni < 4; ni++)
        acc[mi][ni] = __builtin_amdgcn_mfma_f32_16x16x32_bf16(
            a0[mi], b0[ni], acc[mi][ni], 0, 0, 0);
#pragma unroll
    for (int i = 0; i < 4; i++) {
      a1[i] = *(const v8s*)(pa1 + i * 16 * 64);
      b1[i] = *(const v8s*)(pb1 + i * 16 * 64);
    }
#pragma unroll
    for (int mi = 0; mi < 4; mi++)
#pragma unroll
      for (int ni = 0; ni < 4; ni++)
        acc[mi][ni] = __builtin_amdgcn_mfma_f32_16x16x32_bf16(
            a1[mi], b1[ni], acc[mi][ni], 0, 0, 0);
    __syncthreads();
  }

  float bvv[4];
#pragma unroll
  for (int ni = 0; ni < 4; ni++) {
    const int col = n0 + wn + ni * 16 + lrow;
    bvv[ni] = 0.f;
    if (MODE == MODE_RELU) bvv[ni] = bias[col];
    else if (col < n_store) bvv[ni] = bias[col];
  }

#pragma unroll
  for (int ni = 0; ni < 4; ni++) {
    const int col = n0 + wn + ni * 16 + lrow;
#pragma unroll
    for (int mi = 0; mi < 4; mi++) {
      const int rowb = m0 + wm + mi * 16 + quad * 4;
#pragma unroll
      for (int r = 0; r < 4; r++) {
        const int row = rowb + r;
        const float v = acc[mi][ni][r] + bvv[ni];
        if (MODE == MODE_RELU) {
          ((__hip_bfloat16*)Cout)[(size_t)row * ldc + col] =
              __float2bfloat16(v > 0.f ? v : 0.f);
        } else {
          if (col < n_store)
            ((float*)Cout)[(size_t)row * ldc + col] = v;
        }
      }
    }
  }

  if (WT) {
    char* sT = smem;  // 128 x 144, reuses staging LDS (K-loop done)
#pragma unroll
    for (int ni = 0; ni < 4; ni++) {
      const int c = wn + ni * 16 + lrow;
#pragma unroll
      for (int mi = 0; mi < 4; mi++) {
        const int r = wm + mi * 16 + quad * 4;
        char4 bits;
        bits.x = (acc[mi][ni][0] + bvv[ni] > 0.f) ? 1 : 0;
        bits.y = (acc[mi][ni][1] + bvv[ni] > 0.f) ? 1 : 0;
        bits.z = (acc[mi][ni][2] + bvv[ni] > 0.f) ? 1 : 0;
        bits.w = (acc[mi][ni][3] + bvv[ni] > 0.f) ? 1 : 0;
        *(char4*)&sT[c * 144 + r] = bits;
      }
    }
    __syncthreads();
    const int c2 = t >> 1;
    const int hf = (t & 1) * 64;
    char* dst = Tout + (size_t)(n0 + c2) * 8192 + m0 + hf;
    const char* src = sT + c2 * 144 + hf;
#pragma unroll
    for (int j = 0; j < 4; j++)
      *(int4*)(dst + j * 16) = *(const int4*)(src + j * 16);
  }
}

// ---------------- int8 coact gemm (BK=128, swizzled, partial-store) -------
__global__ __launch_bounds__(256) void gemm_nt_i8(
    const char* __restrict__ A, const char* __restrict__ B,
    float* __restrict__ P, int M, int N, int Kc, int n_store, size_t slice) {
  __shared__ char sA[128 * 128];
  __shared__ char sB[128 * 128];
  const int t = threadIdx.x;
  const int m0 = blockIdx.y * 128;
  const int n0 = blockIdx.x * 128;
  const int kbeg = blockIdx.z * Kc;
  const int kend = kbeg + Kc;
  const size_t K = (size_t)Kc * gridDim.z;
  float* __restrict__ Pz = P + (size_t)blockIdx.z * slice;

  const char* aG[4];
  const char* bG[4];
  char* lA[4];
  char* lB[4];
#pragma unroll
  for (int j = 0; j < 4; j++) {
    const int c = j * 256 + t;
    const int row = c >> 3;
    const int g = (c & 7) ^ (row & 7);
    aG[j] = A + (size_t)(m0 + row) * K + g * 16;
    bG[j] = B + (size_t)(n0 + row) * K + g * 16;
    lA[j] = sA + c * 16;
    lB[j] = sB + c * 16;
  }

  const int lane = t & 63;
  const int wave = t >> 6;
  const int wm = (wave & 1) * 64;
  const int wn = (wave >> 1) * 64;
  const int lrow = lane & 15;
  const int quad = lane >> 4;

  const int g0 = quad ^ (lrow & 7);
  const char* pa0 = sA + (wm + lrow) * 128 + g0 * 16;
  const char* pa1 = sA + (wm + lrow) * 128 + (g0 ^ 4) * 16;
  const char* pb0 = sB + (wn + lrow) * 128 + g0 * 16;
  const char* pb1 = sB + (wn + lrow) * 128 + (g0 ^ 4) * 16;

  v4i acc[4][4] = {};

  for (int k0 = kbeg; k0 < kend; k0 += 128) {
#pragma unroll
    for (int j = 0; j < 4; j++) {
      async_cp16(aG[j] + k0, lA[j]);
      async_cp16(bG[j] + k0, lB[j]);
    }
    __syncthreads();

    v4i a0[4], b0[4], a1[4], b1[4];
#pragma unroll
    for (int i = 0; i < 4; i++) {
      a0[i] = *(const v4i*)(pa0 + i * 16 * 128);
      b0[i] = *(const v4i*)(pb0 + i * 16 * 128);
    }
#pragma unroll
    for (int mi = 0; mi < 4; mi++)
#pragma unroll
      for (int ni = 0; ni < 4; ni++)
        acc[mi][ni] = __builtin_amdgcn_mfma_i32_16x16x64_i8(
            a0[mi], b0[ni], acc[mi][ni], 0, 0, 0);
#pragma unroll
    for (int i = 0; i < 4; i++) {
      a1[i] = *(const v4i*)(pa1 + i * 16 * 128);
      b1[i] = *(const v4i*)(pb1 + i * 16 * 128);
    }
#pragma unroll
    for (int mi = 0; mi < 4; mi++)
#pragma unroll
      for (int ni = 0; ni < 4; ni++)
        acc[mi][ni] = __builtin_amdgcn_mfma_i32_16x16x64_i8(
            a1[mi], b1[ni], acc[mi][ni], 0, 0, 0);
    __syncthreads();
  }

#pragma unroll
  for (int ni = 0; ni < 4; ni++) {
    const int col = n0 + wn + ni * 16 + lrow;
    if (col >= n_store) continue;
#pragma unroll
    for (int mi = 0; mi < 4; mi++) {
      const int rowb = m0 + wm + mi * 16 + quad * 4;
#pragma unroll
      for (int r = 0; r < 4; r++) {
        Pz[(size_t)(rowb + r) * n_store + col] = (float)acc[mi][ni][r];
      }
    }
  }
}

template <int Z>
__global__ __launch_bounds__(256) void reduce_part(
    const float* __restrict__ P, float* __restrict__ out, int n4, size_t slice) {
  const int i = blockIdx.x * 256 + threadIdx.x;
  if (i >= n4) return;
  float4 s = ((const float4*)P)[i];
#pragma unroll
  for (int z = 1; z < Z; z++) {
    const float4 v = ((const float4*)(P + (size_t)z * slice))[i];
    s.x += v.x; s.y += v.y; s.z += v.z; s.w += v.w;
  }
  ((float4*)out)[i] = s;
}

// ---------------------------------------------------------------------------
__global__ __launch_bounds__(256) void transpose_bin8f(
    const float* __restrict__ in, char* __restrict__ out,
    int R, int ldin, int Cphys) {
  __shared__ char tile[64][65];
  const int c0 = blockIdx.x * 64;
  const int r0 = blockIdx.y * 64;
  const int tx = threadIdx.x & 63;
  const int ty = threadIdx.x >> 6;
#pragma unroll
  for (int i = 0; i < 64; i += 4) {
    const int c = c0 + tx;
    const int r = r0 + ty + i;
    float v = 0.f;
    if (c < Cphys) v = in[(size_t)r * ldin + c];
    tile[ty + i][tx] = (v > 0.f) ? 1 : 0;
  }
  __syncthreads();
  const int u = threadIdx.x & 15;
  const int cg = threadIdx.x >> 4;
#pragma unroll
  for (int i = 0; i < 64; i += 16) {
    const int col = cg + i;
    char4 v;
    v.x = tile[4 * u + 0][col];
    v.y = tile[4 * u + 1][col];
    v.z = tile[4 * u + 2][col];
    v.w = tile[4 * u + 3][col];
    *(char4*)&out[(size_t)(c0 + col) * R + r0 + 4 * u] = v;
  }
}

struct Cvt4 {
  const float* src[4];
  __hip_bfloat16* dst[4];
  int n4[4];
};
__global__ __launch_bounds__(256) void f32_to_bf16_multi(Cvt4 c) {
  int i = blockIdx.x * 256 + threadIdx.x;
#pragma unroll
  for (int s = 0; s < 4; s++) {
    if (i < c.n4[s]) {
      const float4 v = ((const float4*)c.src[s])[i];
      union { __hip_bfloat16 h[4]; ushort4 u; } cv;
      cv.h[0] = __float2bfloat16(v.x);
      cv.h[1] = __float2bfloat16(v.y);
      cv.h[2] = __float2bfloat16(v.z);
      cv.h[3] = __float2bfloat16(v.w);
      ((ushort4*)c.dst[s])[i] = cv.u;
      return;
    }
    i -= c.n4[s];
  }
}

// ---------------------------------------------------------------------------
extern "C" void kernel_launch(void* const* d_in, const int* in_sizes, int n_in,
                              void* d_out, int out_size, void* d_ws, size_t ws_size,
                              hipStream_t stream) {
  const float* x  = (const float*)d_in[0];
  const float* W1 = (const float*)d_in[1];
  const float* b1 = (const float*)d_in[2];
  const float* W2 = (const float*)d_in[3];
  const float* b2 = (const float*)d_in[4];
  const float* W3 = (const float*)d_in[5];
  const float* b3 = (const float*)d_in[6];

  float* logits = (float*)d_out;                        // [8192,1000]
  float* coact0 = logits + (size_t)8192 * 1000;         // [1024,2048]
  float* coact1 = coact0 + (size_t)1024 * 2048;         // [2048,2048]
  float* coact2 = coact1 + (size_t)2048 * 2048;         // [2048,1000]

  char* ws = (char*)d_ws;
  size_t off = 0;
  auto alloc = [&](size_t bytes) {
    char* p = ws + off;
    off += (bytes + 255) & ~(size_t)255;
    return p;
  };
  __hip_bfloat16* X   = (__hip_bfloat16*)alloc((size_t)8192 * 1024 * 2);  // 16MiB
  __hip_bfloat16* W1b = (__hip_bfloat16*)alloc((size_t)2048 * 1024 * 2);  //  4MiB
  __hip_bfloat16* W2b = (__hip_bfloat16*)alloc((size_t)2048 * 2048 * 2);  //  8MiB
  __hip_bfloat16* W3b = (__hip_bfloat16*)alloc((size_t)1024 * 2048 * 2);  //  4MiB
  __hip_bfloat16* A1  = (__hip_bfloat16*)alloc((size_t)8192 * 2048 * 2);  // 32MiB
  __hip_bfloat16* A2  = (__hip_bfloat16*)alloc((size_t)8192 * 2048 * 2);  // 32MiB
  char* T0 = (char*)alloc((size_t)1024 * 8192);  // Act0^T i8, 8MiB
  char* T1 = (char*)alloc((size_t)2048 * 8192);  // Act1^T i8, 16MiB
  char* T2 = (char*)X;    // Act2^T [2048,8192] i8 (X dead after gemm1)
  char* T3 = (char*)W2b;  // Act3^T [1024,8192] i8 (W2b dead after gemm2)
  float* P = (float*)A1;  // split-K partials (A1 dead after gemm2)

  const dim3 blk(256);

  {
    Cvt4 c;
    c.src[0] = x;  c.dst[0] = X;   c.n4[0] = 8192 * 1024 / 4;
    c.src[1] = W1; c.dst[1] = W1b; c.n4[1] = 2048 * 1024 / 4;
    c.src[2] = W2; c.dst[2] = W2b; c.n4[2] = 2048 * 2048 / 4;
    c.src[3] = W3; c.dst[3] = W3b; c.n4[3] = 1000 * 2048 / 4;
    const int total = c.n4[0] + c.n4[1] + c.n4[2] + c.n4[3];
    f32_to_bf16_multi<<<(total + 255) / 256, blk, 0, stream>>>(c);
  }

  // Act0^T = (x>0)^T  [1024, 8192] i8
  transpose_bin8f<<<dim3(16, 128), blk, 0, stream>>>(x, T0, 8192, 1024, 1024);

  // z1 = X @ W1^T + b1; A1 = relu bf16; T1 = bits^T (single-barrier 256^2)
  gemm256_relu_wt<<<dim3(8, 32), dim3(512), 0, stream>>>(
      X, W1b, b1, A1, T1, 1024, 2048);

  // z2 = A1 @ W2^T + b2; A2 = relu bf16; T2 = bits^T
  gemm256_relu_wt<<<dim3(8, 32), dim3(512), 0, stream>>>(
      A1, W2b, b2, A2, T2, 2048, 2048);

  // logits = A2 @ W3^T + b3 (store cols<1000); T3 = bits^T
  gemm_nt<MODE_LOGITS, 1><<<dim3(8, 64), blk, 0, stream>>>(
      A2, W3b, b3, logits, T3, 8192, 1024, 2048, 1000, 1000);

  // coact0 = Act0^T @ Act1 -> [1024,2048]; z=4
  gemm_nt_i8<<<dim3(16, 8, 4), blk, 0, stream>>>(T0, T1, P,
                                                 1024, 2048, 2048, 2048,
                                                 (size_t)1024 * 2048);
  reduce_part<4><<<1024 * 2048 / 4 / 256, blk, 0, stream>>>(
      P, coact0, 1024 * 2048 / 4, (size_t)1024 * 2048);

  // coact1 = Act1^T @ Act2 -> [2048,2048]; z=2
  gemm_nt_i8<<<dim3(16, 16, 2), blk, 0, stream>>>(T1, T2, P,
                                                  2048, 2048, 4096, 2048,
                                                  (size_t)2048 * 2048);
  reduce_part<2><<<2048 * 2048 / 4 / 256, blk, 0, stream>>>(
      P, coact1, 2048 * 2048 / 4, (size_t)2048 * 2048);

  // coact2 = Act2^T @ Act3 -> [2048,1000]; z=4
  gemm_nt_i8<<<dim3(8, 16, 4), blk, 0, stream>>>(T2, T3, P,
                                                 2048, 1024, 2048, 1000,
                                                 (size_t)2048 * 1000);
  reduce_part<4><<<2048 * 1000 / 4 / 256, blk, 0, stream>>>(
      P, coact2, 2048 * 1000 / 4, (size_t)2048 * 1000);
}

// Round 6
// 413.927 us; speedup vs baseline: 1.1016x; 1.1016x over previous
//
#include <hip/hip_runtime.h>
#include <hip/hip_bf16.h>

// ---------------------------------------------------------------------------
// HebbianNetwork: logits + 3 coactivation matrices.
//   B=8192, D_IN=1024, H1=H2=2048, N_CLS=1000
// Forward: bf16 MFMA (16x16x32), 256^2 8-phase (R12 discipline: per-phase
// WAITV pre-BAR + [rd][stage][BAR][lgkm0][MFMA][BAR]) — 937 TF, proven.
// R13 (single-barrier windows + alo dbuf) regressed (reg pressure): reverted.
// R14: forward = R12 exact; coacts upgraded BK=128 -> 256 (halves sync
// overhead per byte; 64KB LDS/block, 2 blocks/CU; swizzle generalized to
// 16 granules/row — bit3 (k-slice) passes through the 3-bit XOR).
// gemm3 (N=1024) stays on the 128^2 2-phase kernel.
// ---------------------------------------------------------------------------

typedef short v8s __attribute__((ext_vector_type(8)));
typedef float v4f __attribute__((ext_vector_type(4)));
typedef int v4i __attribute__((ext_vector_type(4)));

enum { MODE_RELU = 0, MODE_LOGITS = 1 };

__device__ __forceinline__ void async_cp16(const void* gsrc, void* ldst) {
  __builtin_amdgcn_global_load_lds(
      (const __attribute__((address_space(1))) void*)gsrc,
      (__attribute__((address_space(3))) void*)ldst, 16, 0, 0);
}

#define FENCE asm volatile("" ::: "memory")
#define BAR()                         \
  do {                                \
    FENCE;                            \
    __builtin_amdgcn_s_barrier();     \
    FENCE;                            \
  } while (0)
#define WAITL()                                          \
  do {                                                   \
    asm volatile("s_waitcnt lgkmcnt(0)" ::: "memory");   \
    __builtin_amdgcn_sched_barrier(0);                   \
  } while (0)
#define WAITV(n)                                           \
  do {                                                     \
    asm volatile("s_waitcnt vmcnt(" #n ")" ::: "memory");  \
    __builtin_amdgcn_sched_barrier(0);                     \
  } while (0)
#define PRIO1 __builtin_amdgcn_s_setprio(1)
#define PRIO0 __builtin_amdgcn_s_setprio(0)

// ---------------- 256^2 8-phase bf16 gemm (R12, proven) -------------------
// C[M,N] = relu(A[M,K] @ B[N,K]^T + bias) -> bf16 Cout [M, ldc]
// Tout[col][row] = (z>0) int8, row stride 8192. Requires M%256==0, N%256==0,
// K%128==0, K>=256. Grid (N/256, M/256), 512 threads.
//
// Tile t (4 phases, buf b=t&1), quadrant rotation (no reg collisions):
//  P0: rd alo(8) | q3(t-1)=ahi*bhi     P1: rd blo(4) | q0=alo*blo
//  P2: rd ahi(8) | q1=ahi*blo          P3: rd bhi(4) | q2=alo*bhi
// Stage slots (iter i = tiles e=2i buf0, o=2i+1 buf1; 1 half = 2 loads/phase):
//  ph0: pA1h<-Ahi(o)   ph1: pB1l<-Blo(o)   ph2: pB1h<-Bhi(o)
//  ph3: pA0l<-Alo(e+2) ph4: pA0h<-Ahi(e+2) ph5: pB0l<-Blo(e+2)
//  ph6: pB0h<-Bhi(e+2) ph7: pA1l<-Alo(o+2)
// WAR: pane staged >= 1 phase after its last read's drain (WAITL) + BAR.
// RAW: each phase ends with WAITV(n) BEFORE its BAR, validating the pane the
// NEXT phase reads (per-wave own-loads + barrier = collective). n = 2 x
// (#halves staged after the target): 6,10,8,8,6,10,8,8; prologue 8.
// Prologue stage order: Alo0,Ahi0,Blo0,Bhi0,Alo1. Last iter: clamped stage
// sources (tile 0, landed, never read); WAITV(0)+BAR guards sT LDS reuse.
__global__ __launch_bounds__(512, 2) void gemm256_relu_wt(
    const __hip_bfloat16* __restrict__ A, const __hip_bfloat16* __restrict__ B,
    const float* __restrict__ bias, __hip_bfloat16* __restrict__ Cout,
    char* __restrict__ Tout, int K, int ldc) {
  __shared__ char smem[131072];
  const int t = threadIdx.x;
  const int m0 = blockIdx.y * 256;
  const int n0 = blockIdx.x * 256;

  // staging: half-tile = 128 rows x 64 cols bf16 = 1024 chunks(16B);
  // thread t owns chunks c0=t, c1=512+t. LDS dest linear (c*16), global
  // source granule XOR-swizzled: g = (c&7) ^ (row&7).
  const int c0 = t, c1 = 512 + t;
  const int r0s = c0 >> 3, r1s = c1 >> 3;
  const int goff0 = r0s * K + ((c0 & 7) ^ (r0s & 7)) * 8;
  const int goff1 = r1s * K + ((c1 & 7) ^ (r1s & 7)) * 8;
  const int loff0 = c0 * 16, loff1 = c1 * 16;

  const __hip_bfloat16* const Abase = A + (size_t)m0 * K;
  const __hip_bfloat16* const Bbase = B + (size_t)n0 * K;
  const size_t hk = (size_t)128 * K;  // element offset of rows 128..255

  // LDS panes (16KB each): [buf][A/B][lo/hi]
  char* const pA0l = smem;
  char* const pA0h = smem + 16384;
  char* const pB0l = smem + 32768;
  char* const pB0h = smem + 49152;
  char* const pA1l = smem + 65536;
  char* const pA1h = smem + 81920;
  char* const pB1l = smem + 98304;
  char* const pB1h = smem + 114688;

  const int lane = t & 63;
  const int wave = t >> 6;
  const int wm = wave >> 2;  // 0..1, M half (128 rows)
  const int wn = wave & 3;   // 0..3, N quarter (64 cols)
  const int lrow = lane & 15;
  const int quad = lane >> 4;
  // reader: content granule gk = ks*4+quad stored at slot gk ^ (row&7)
  const int sl0 = ((quad ^ (lrow & 7)) * 16);
  const int sl1 = (((quad + 4) ^ (lrow & 7)) * 16);
  const int ardA = (wm * 128 + lrow) * 128;  // byte, row stride 128B
  const int ardB = (wn * 64 + lrow) * 128;

  v4f acc[8][4] = {};
  v8s alo[4][2], ahi[4][2], blo[2][2], bhi[2][2];

#define STAGE(dst, src)                                               \
  do {                                                                \
    async_cp16((const void*)((src) + goff0), (void*)((dst) + loff0)); \
    async_cp16((const void*)((src) + goff1), (void*)((dst) + loff1)); \
  } while (0)

#define LDA_H(dst, hh, bb)                                                   \
  _Pragma("unroll") for (int mi = 0; mi < 4; mi++) {                         \
    dst[mi][0] =                                                             \
        *(const v8s*)(smem + (bb) + ardA + (hh)*8192 + mi * 2048 + sl0);     \
    dst[mi][1] =                                                             \
        *(const v8s*)(smem + (bb) + ardA + (hh)*8192 + mi * 2048 + sl1);     \
  }

#define LDB_P(dst, pp, bb)                                                    \
  _Pragma("unroll") for (int ni = 0; ni < 2; ni++) {                          \
    dst[ni][0] = *(const v8s*)(smem + (bb) + 32768 + ardB +                   \
                               ((pp)*2 + ni) * 2048 + sl0);                   \
    dst[ni][1] = *(const v8s*)(smem + (bb) + 32768 + ardB +                   \
                               ((pp)*2 + ni) * 2048 + sl1);                   \
  }

#define MMA_Q(af, bf, MB, NB)                                               \
  _Pragma("unroll") for (int mi = 0; mi < 4; mi++)                          \
      _Pragma("unroll") for (int ni = 0; ni < 2; ni++)                      \
          _Pragma("unroll") for (int ks = 0; ks < 2; ks++)                  \
              acc[(MB) + mi][(NB) + ni] =                                   \
      __builtin_amdgcn_mfma_f32_16x16x32_bf16(                              \
          af[mi][ks], bf[ni][ks], acc[(MB) + mi][(NB) + ni], 0, 0, 0);

  // ---- prologue: Alo0, Ahi0, Blo0, Bhi0, Alo1 (order matters for vmcnt) --
  STAGE(pA0l, Abase);
  STAGE(pA0h, Abase + hk);
  STAGE(pB0l, Bbase);
  STAGE(pB0h, Bbase + hk);
  STAGE(pA1l, Abase + 64);
  WAITV(8);  // validates Alo0 (ph0's pane) — pre-BAR, collective after BAR
  BAR();

  const int NI = K >> 7;  // iterations of 2 K-tiles
  const int NT = K >> 6;  // K-tiles

#pragma unroll 1
  for (int i = 0; i < NI; ++i) {
    const int to = 2 * i + 1;                         // always < NT
    const int t2 = (2 * i + 2 < NT) ? 2 * i + 2 : 0;  // clamped
    const int t3 = (2 * i + 3 < NT) ? 2 * i + 3 : 0;
    const __hip_bfloat16* Ao = Abase + to * 64;
    const __hip_bfloat16* Bo = Bbase + to * 64;
    const __hip_bfloat16* A2 = Abase + t2 * 64;
    const __hip_bfloat16* B2 = Bbase + t2 * 64;
    const __hip_bfloat16* A3 = Abase + t3 * 64;
    // ph0: rd alo(e) | stage Ahi(o) | WAITV->Blo(e) | q3(prev odd)
    LDA_H(alo, 0, 0);
    STAGE(pA1h, Ao + hk);
    WAITV(6);
    BAR();
    WAITL();
    if (i) { PRIO1; MMA_Q(ahi, bhi, 4, 2); PRIO0; }
    BAR();
    // ph1: rd blo(e) | stage Blo(o) | WAITV->Ahi(e) (no-op) | q0(e)
    LDB_P(blo, 0, 0);
    STAGE(pB1l, Bo);
    WAITV(10);
    BAR();
    WAITL();
    PRIO1; MMA_Q(alo, blo, 0, 0); PRIO0;
    BAR();
    // ph2: rd ahi(e) | stage Bhi(o) | WAITV->Bhi(e) | q1(e)
    LDA_H(ahi, 1, 0);
    STAGE(pB1h, Bo + hk);
    WAITV(8);
    BAR();
    WAITL();
    PRIO1; MMA_Q(ahi, blo, 4, 0); PRIO0;
    BAR();
    // ph3: rd bhi(e) | stage Alo(e+2) | WAITV->Alo(o) | q2(e)
    LDB_P(bhi, 1, 0);
    STAGE(pA0l, A2);
    WAITV(8);
    BAR();
    WAITL();
    PRIO1; MMA_Q(alo, bhi, 0, 2); PRIO0;
    BAR();
    // ph4: rd alo(o) | stage Ahi(e+2) | WAITV->Blo(o) | q3(e)
    LDA_H(alo, 0, 65536);
    STAGE(pA0h, A2 + hk);
    WAITV(6);
    BAR();
    WAITL();
    PRIO1; MMA_Q(ahi, bhi, 4, 2); PRIO0;
    BAR();
    // ph5: rd blo(o) | stage Blo(e+2) | WAITV->Ahi(o) (no-op) | q0(o)
    LDB_P(blo, 0, 65536);
    STAGE(pB0l, B2);
    WAITV(10);
    BAR();
    WAITL();
    PRIO1; MMA_Q(alo, blo, 0, 0); PRIO0;
    BAR();
    // ph6: rd ahi(o) | stage Bhi(e+2) | WAITV->Bhi(o) | q1(o)
    LDA_H(ahi, 1, 65536);
    STAGE(pB0h, B2 + hk);
    WAITV(8);
    BAR();
    WAITL();
    PRIO1; MMA_Q(ahi, blo, 4, 0); PRIO0;
    BAR();
    // ph7: rd bhi(o) | stage Alo(o+2) | WAITV->Alo(e') | q2(o)
    LDB_P(bhi, 1, 65536);
    STAGE(pA1l, A3);
    WAITV(8);
    BAR();
    WAITL();
    PRIO1; MMA_Q(alo, bhi, 0, 2); PRIO0;
    BAR();
  }
  // final q3(tile NT-1), regs only
  PRIO1; MMA_Q(ahi, bhi, 4, 2); PRIO0;
  WAITV(0);  // drain clamped stage loads before LDS reuse (sT)
  BAR();
#undef STAGE
#undef LDA_H
#undef LDB_P
#undef MMA_Q

  // ---- epilogue ----
  float bv[4];
#pragma unroll
  for (int ni = 0; ni < 4; ni++) bv[ni] = bias[n0 + wn * 64 + ni * 16 + lrow];

  // C/D layout: col = lane&15, row = quad*4 + reg
#pragma unroll
  for (int mi = 0; mi < 8; mi++) {
    const int rowb = m0 + wm * 128 + mi * 16 + quad * 4;
#pragma unroll
    for (int ni = 0; ni < 4; ni++) {
      const int col = n0 + wn * 64 + ni * 16 + lrow;
#pragma unroll
      for (int r = 0; r < 4; r++) {
        const float v = acc[mi][ni][r] + bv[ni];
        Cout[(size_t)(rowb + r) * ldc + col] =
            __float2bfloat16(v > 0.f ? v : 0.f);
      }
    }
  }

  // fused binarized transpose: T[n0+c][m0+r] = (z > 0), via LDS 256x272
  char* const sT = smem;
#pragma unroll
  for (int ni = 0; ni < 4; ni++) {
    const int c = wn * 64 + ni * 16 + lrow;
#pragma unroll
    for (int mi = 0; mi < 8; mi++) {
      const int rw = wm * 128 + mi * 16 + quad * 4;
      char4 bits;
      bits.x = (acc[mi][ni][0] + bv[ni] > 0.f) ? 1 : 0;
      bits.y = (acc[mi][ni][1] + bv[ni] > 0.f) ? 1 : 0;
      bits.z = (acc[mi][ni][2] + bv[ni] > 0.f) ? 1 : 0;
      bits.w = (acc[mi][ni][3] + bv[ni] > 0.f) ? 1 : 0;
      *(char4*)&sT[c * 272 + rw] = bits;
    }
  }
  __syncthreads();
  const int rw2 = t >> 1;
  const int hf = (t & 1) * 128;
  char* dst = Tout + (size_t)(n0 + rw2) * 8192 + m0 + hf;
  const char* src = sT + rw2 * 272 + hf;
#pragma unroll
  for (int j = 0; j < 8; j++)
    *(int4*)(dst + j * 16) = *(const int4*)(src + j * 16);
}

// ---------------- bf16 forward gemm (BK=64, swizzled, 128^2) --------------
// Retained for gemm3 (N=1024: 256^2 grid would only be 128 blocks).
template <int MODE, int WT>
__global__ __launch_bounds__(256) void gemm_nt(
    const __hip_bfloat16* __restrict__ A, const __hip_bfloat16* __restrict__ B,
    const float* __restrict__ bias, void* __restrict__ Cout,
    char* __restrict__ Tout, int M, int N, int K, int n_store, int ldc) {
  __shared__ char smem[32768];
  __hip_bfloat16* sA = (__hip_bfloat16*)smem;           // 16KB
  __hip_bfloat16* sB = (__hip_bfloat16*)(smem + 16384); // 16KB
  const int t = threadIdx.x;
  const int m0 = blockIdx.y * 128;
  const int n0 = blockIdx.x * 128;

  const __hip_bfloat16* aG[4];
  const __hip_bfloat16* bG[4];
  char* lA[4];
  char* lB[4];
#pragma unroll
  for (int j = 0; j < 4; j++) {
    const int c = j * 256 + t;
    const int row = c >> 3;
    const int g = (c & 7) ^ (row & 7);
    aG[j] = A + (size_t)(m0 + row) * K + g * 8;
    bG[j] = B + (size_t)(n0 + row) * K + g * 8;
    lA[j] = (char*)sA + c * 16;
    lB[j] = (char*)sB + c * 16;
  }

  const int lane = t & 63;
  const int wave = t >> 6;
  const int wm = (wave & 1) * 64;
  const int wn = (wave >> 1) * 64;
  const int lrow = lane & 15;
  const int quad = lane >> 4;

  const int g0 = quad ^ (lrow & 7);
  const __hip_bfloat16* pa0 = sA + (wm + lrow) * 64 + g0 * 8;
  const __hip_bfloat16* pa1 = sA + (wm + lrow) * 64 + (g0 ^ 4) * 8;
  const __hip_bfloat16* pb0 = sB + (wn + lrow) * 64 + g0 * 8;
  const __hip_bfloat16* pb1 = sB + (wn + lrow) * 64 + (g0 ^ 4) * 8;

  v4f acc[4][4] = {};

  for (int k0 = 0; k0 < K; k0 += 64) {
#pragma unroll
    for (int j = 0; j < 4; j++) {
      async_cp16(aG[j] + k0, lA[j]);
      async_cp16(bG[j] + k0, lB[j]);
    }
    __syncthreads();

    v8s a0[4], b0[4], a1[4], b1[4];
#pragma unroll
    for (int i = 0; i < 4; i++) {
      a0[i] = *(const v8s*)(pa0 + i * 16 * 64);
      b0[i] = *(const v8s*)(pb0 + i * 16 * 64);
    }
#pragma unroll
    for (int mi = 0; mi < 4; mi++)
#pragma unroll
      for (int ni = 0; ni < 4; ni++)
        acc[mi][ni] = __builtin_amdgcn_mfma_f32_16x16x32_bf16(
            a0[mi], b0[ni], acc[mi][ni], 0, 0, 0);
#pragma unroll
    for (int i = 0; i < 4; i++) {
      a1[i] = *(const v8s*)(pa1 + i * 16 * 64);
      b1[i] = *(const v8s*)(pb1 + i * 16 * 64);
    }
#pragma unroll
    for (int mi = 0; mi < 4; mi++)
#pragma unroll
      for (int ni = 0; ni < 4; ni++)
        acc[mi][ni] = __builtin_amdgcn_mfma_f32_16x16x32_bf16(
            a1[mi], b1[ni], acc[mi][ni], 0, 0, 0);
    __syncthreads();
  }

  float bvv[4];
#pragma unroll
  for (int ni = 0; ni < 4; ni++) {
    const int col = n0 + wn + ni * 16 + lrow;
    bvv[ni] = 0.f;
    if (MODE == MODE_RELU) bvv[ni] = bias[col];
    else if (col < n_store) bvv[ni] = bias[col];
  }

#pragma unroll
  for (int ni = 0; ni < 4; ni++) {
    const int col = n0 + wn + ni * 16 + lrow;
#pragma unroll
    for (int mi = 0; mi < 4; mi++) {
      const int rowb = m0 + wm + mi * 16 + quad * 4;
#pragma unroll
      for (int r = 0; r < 4; r++) {
        const int row = rowb + r;
        const float v = acc[mi][ni][r] + bvv[ni];
        if (MODE == MODE_RELU) {
          ((__hip_bfloat16*)Cout)[(size_t)row * ldc + col] =
              __float2bfloat16(v > 0.f ? v : 0.f);
        } else {
          if (col < n_store)
            ((float*)Cout)[(size_t)row * ldc + col] = v;
        }
      }
    }
  }

  if (WT) {
    char* sT = smem;  // 128 x 144, reuses staging LDS (K-loop done)
#pragma unroll
    for (int ni = 0; ni < 4; ni++) {
      const int c = wn + ni * 16 + lrow;
#pragma unroll
      for (int mi = 0; mi < 4; mi++) {
        const int r = wm + mi * 16 + quad * 4;
        char4 bits;
        bits.x = (acc[mi][ni][0] + bvv[ni] > 0.f) ? 1 : 0;
        bits.y = (acc[mi][ni][1] + bvv[ni] > 0.f) ? 1 : 0;
        bits.z = (acc[mi][ni][2] + bvv[ni] > 0.f) ? 1 : 0;
        bits.w = (acc[mi][ni][3] + bvv[ni] > 0.f) ? 1 : 0;
        *(char4*)&sT[c * 144 + r] = bits;
      }
    }
    __syncthreads();
    const int c2 = t >> 1;
    const int hf = (t & 1) * 64;
    char* dst = Tout + (size_t)(n0 + c2) * 8192 + m0 + hf;
    const char* src = sT + c2 * 144 + hf;
#pragma unroll
    for (int j = 0; j < 4; j++)
      *(int4*)(dst + j * 16) = *(const int4*)(src + j * 16);
  }
}

// ---------------- int8 coact gemm (BK=256, swizzled, partial-store) -------
// P_z[M, n_store] = A[M, kz..] @ B[N, kz..]^T for slice z = blockIdx.z.
// A,B int8 (0/1) row-major inner-K. Kc % 256 == 0. Row = 256B = 16 granules;
// swizzle slot = g ^ (row&7) (3-bit XOR; bit3 = k-slice passes through).
// 64KB LDS/block -> 2 blocks/CU. Exact (i32 partials < 2^24).
__global__ __launch_bounds__(256) void gemm_nt_i8(
    const char* __restrict__ A, const char* __restrict__ B,
    float* __restrict__ P, int M, int N, int Kc, int n_store, size_t slice) {
  __shared__ char sA[128 * 256];  // 32KB
  __shared__ char sB[128 * 256];  // 32KB
  const int t = threadIdx.x;
  const int m0 = blockIdx.y * 128;
  const int n0 = blockIdx.x * 128;
  const int kbeg = blockIdx.z * Kc;
  const int kend = kbeg + Kc;
  const size_t K = (size_t)Kc * gridDim.z;  // full K (row stride, bytes)
  float* __restrict__ Pz = P + (size_t)blockIdx.z * slice;

  // staging: 2048 chunks(16B)/tile; thread t owns chunks j*256+t, j=0..7.
  const char* aG[8];
  const char* bG[8];
  char* lA[8];
  char* lB[8];
#pragma unroll
  for (int j = 0; j < 8; j++) {
    const int c = j * 256 + t;
    const int row = c >> 4;                  // 16 granules per row
    const int g = (c & 15) ^ (row & 7);      // bijective within row
    aG[j] = A + (size_t)(m0 + row) * K + g * 16;
    bG[j] = B + (size_t)(n0 + row) * K + g * 16;
    lA[j] = sA + c * 16;
    lB[j] = sB + c * 16;
  }

  const int lane = t & 63;
  const int wave = t >> 6;
  const int wm = (wave & 1) * 64;
  const int wn = (wave >> 1) * 64;
  const int lrow = lane & 15;
  const int quad = lane >> 4;

  // reader: k-slice ks (0..3) content granule gk = ks*4 + quad, stored at
  // slot gk ^ (lrow&7). ks*4 has bits 2,3; XOR only low 3 bits -> slot =
  // (quad ^ (lrow&7)) ^ (ks*4) computed on the granule index.
  const int g0 = quad ^ (lrow & 7);
  const char* pa[4];
  const char* pb[4];
#pragma unroll
  for (int ks = 0; ks < 4; ks++) {
    const int sl = (g0 ^ (ks * 4)) * 16;
    pa[ks] = sA + (wm + lrow) * 256 + sl;
    pb[ks] = sB + (wn + lrow) * 256 + sl;
  }

  v4i acc[4][4] = {};

  for (int k0 = kbeg; k0 < kend; k0 += 256) {
#pragma unroll
    for (int j = 0; j < 8; j++) {
      async_cp16(aG[j] + k0, lA[j]);
      async_cp16(bG[j] + k0, lB[j]);
    }
    __syncthreads();  // compiler emits vmcnt(0) drain before barrier

#pragma unroll
    for (int ks = 0; ks < 4; ks++) {
      v4i a[4], b[4];
#pragma unroll
      for (int i = 0; i < 4; i++) {
        a[i] = *(const v4i*)(pa[ks] + i * 16 * 256);
        b[i] = *(const v4i*)(pb[ks] + i * 16 * 256);
      }
#pragma unroll
      for (int mi = 0; mi < 4; mi++)
#pragma unroll
        for (int ni = 0; ni < 4; ni++)
          acc[mi][ni] = __builtin_amdgcn_mfma_i32_16x16x64_i8(
              a[mi], b[ni], acc[mi][ni], 0, 0, 0);
    }
    __syncthreads();
  }

  // epilogue: C/D layout col=lane&15, row=quad*4+reg; dense [M, n_store]
#pragma unroll
  for (int ni = 0; ni < 4; ni++) {
    const int col = n0 + wn + ni * 16 + lrow;
    if (col >= n_store) continue;
#pragma unroll
    for (int mi = 0; mi < 4; mi++) {
      const int rowb = m0 + wm + mi * 16 + quad * 4;
#pragma unroll
      for (int r = 0; r < 4; r++) {
        Pz[(size_t)(rowb + r) * n_store + col] = (float)acc[mi][ni][r];
      }
    }
  }
}

template <int Z>
__global__ __launch_bounds__(256) void reduce_part(
    const float* __restrict__ P, float* __restrict__ out, int n4, size_t slice) {
  const int i = blockIdx.x * 256 + threadIdx.x;
  if (i >= n4) return;
  float4 s = ((const float4*)P)[i];
#pragma unroll
  for (int z = 1; z < Z; z++) {
    const float4 v = ((const float4*)(P + (size_t)z * slice))[i];
    s.x += v.x; s.y += v.y; s.z += v.z; s.w += v.w;
  }
  ((float4*)out)[i] = s;
}

// ---------------------------------------------------------------------------
__global__ __launch_bounds__(256) void transpose_bin8f(
    const float* __restrict__ in, char* __restrict__ out,
    int R, int ldin, int Cphys) {
  __shared__ char tile[64][65];
  const int c0 = blockIdx.x * 64;
  const int r0 = blockIdx.y * 64;
  const int tx = threadIdx.x & 63;
  const int ty = threadIdx.x >> 6;
#pragma unroll
  for (int i = 0; i < 64; i += 4) {
    const int c = c0 + tx;
    const int r = r0 + ty + i;
    float v = 0.f;
    if (c < Cphys) v = in[(size_t)r * ldin + c];
    tile[ty + i][tx] = (v > 0.f) ? 1 : 0;
  }
  __syncthreads();
  const int u = threadIdx.x & 15;
  const int cg = threadIdx.x >> 4;
#pragma unroll
  for (int i = 0; i < 64; i += 16) {
    const int col = cg + i;
    char4 v;
    v.x = tile[4 * u + 0][col];
    v.y = tile[4 * u + 1][col];
    v.z = tile[4 * u + 2][col];
    v.w = tile[4 * u + 3][col];
    *(char4*)&out[(size_t)(c0 + col) * R + r0 + 4 * u] = v;
  }
}

struct Cvt4 {
  const float* src[4];
  __hip_bfloat16* dst[4];
  int n4[4];
};
__global__ __launch_bounds__(256) void f32_to_bf16_multi(Cvt4 c) {
  int i = blockIdx.x * 256 + threadIdx.x;
#pragma unroll
  for (int s = 0; s < 4; s++) {
    if (i < c.n4[s]) {
      const float4 v = ((const float4*)c.src[s])[i];
      union { __hip_bfloat16 h[4]; ushort4 u; } cv;
      cv.h[0] = __float2bfloat16(v.x);
      cv.h[1] = __float2bfloat16(v.y);
      cv.h[2] = __float2bfloat16(v.z);
      cv.h[3] = __float2bfloat16(v.w);
      ((ushort4*)c.dst[s])[i] = cv.u;
      return;
    }
    i -= c.n4[s];
  }
}

// ---------------------------------------------------------------------------
extern "C" void kernel_launch(void* const* d_in, const int* in_sizes, int n_in,
                              void* d_out, int out_size, void* d_ws, size_t ws_size,
                              hipStream_t stream) {
  const float* x  = (const float*)d_in[0];
  const float* W1 = (const float*)d_in[1];
  const float* b1 = (const float*)d_in[2];
  const float* W2 = (const float*)d_in[3];
  const float* b2 = (const float*)d_in[4];
  const float* W3 = (const float*)d_in[5];
  const float* b3 = (const float*)d_in[6];

  float* logits = (float*)d_out;                        // [8192,1000]
  float* coact0 = logits + (size_t)8192 * 1000;         // [1024,2048]
  float* coact1 = coact0 + (size_t)1024 * 2048;         // [2048,2048]
  float* coact2 = coact1 + (size_t)2048 * 2048;         // [2048,1000]

  char* ws = (char*)d_ws;
  size_t off = 0;
  auto alloc = [&](size_t bytes) {
    char* p = ws + off;
    off += (bytes + 255) & ~(size_t)255;
    return p;
  };
  __hip_bfloat16* X   = (__hip_bfloat16*)alloc((size_t)8192 * 1024 * 2);  // 16MiB
  __hip_bfloat16* W1b = (__hip_bfloat16*)alloc((size_t)2048 * 1024 * 2);  //  4MiB
  __hip_bfloat16* W2b = (__hip_bfloat16*)alloc((size_t)2048 * 2048 * 2);  //  8MiB
  __hip_bfloat16* W3b = (__hip_bfloat16*)alloc((size_t)1024 * 2048 * 2);  //  4MiB
  __hip_bfloat16* A1  = (__hip_bfloat16*)alloc((size_t)8192 * 2048 * 2);  // 32MiB
  __hip_bfloat16* A2  = (__hip_bfloat16*)alloc((size_t)8192 * 2048 * 2);  // 32MiB
  char* T0 = (char*)alloc((size_t)1024 * 8192);  // Act0^T i8, 8MiB
  char* T1 = (char*)alloc((size_t)2048 * 8192);  // Act1^T i8, 16MiB
  char* T2 = (char*)X;    // Act2^T [2048,8192] i8 (X dead after gemm1)
  char* T3 = (char*)W2b;  // Act3^T [1024,8192] i8 (W2b dead after gemm2)
  float* P = (float*)A1;  // split-K partials (A1 dead after gemm2)

  const dim3 blk(256);

  {
    Cvt4 c;
    c.src[0] = x;  c.dst[0] = X;   c.n4[0] = 8192 * 1024 / 4;
    c.src[1] = W1; c.dst[1] = W1b; c.n4[1] = 2048 * 1024 / 4;
    c.src[2] = W2; c.dst[2] = W2b; c.n4[2] = 2048 * 2048 / 4;
    c.src[3] = W3; c.dst[3] = W3b; c.n4[3] = 1000 * 2048 / 4;
    const int total = c.n4[0] + c.n4[1] + c.n4[2] + c.n4[3];
    f32_to_bf16_multi<<<(total + 255) / 256, blk, 0, stream>>>(c);
  }

  // Act0^T = (x>0)^T  [1024, 8192] i8
  transpose_bin8f<<<dim3(16, 128), blk, 0, stream>>>(x, T0, 8192, 1024, 1024);

  // z1 = X @ W1^T + b1; A1 = relu bf16; T1 = bits^T (8-phase 256^2, R12)
  gemm256_relu_wt<<<dim3(8, 32), dim3(512), 0, stream>>>(
      X, W1b, b1, A1, T1, 1024, 2048);

  // z2 = A1 @ W2^T + b2; A2 = relu bf16; T2 = bits^T
  gemm256_relu_wt<<<dim3(8, 32), dim3(512), 0, stream>>>(
      A1, W2b, b2, A2, T2, 2048, 2048);

  // logits = A2 @ W3^T + b3 (store cols<1000); T3 = bits^T
  gemm_nt<MODE_LOGITS, 1><<<dim3(8, 64), blk, 0, stream>>>(
      A2, W3b, b3, logits, T3, 8192, 1024, 2048, 1000, 1000);

  // coact0 = Act0^T @ Act1 -> [1024,2048]; z=4 (Kc=2048)
  gemm_nt_i8<<<dim3(16, 8, 4), blk, 0, stream>>>(T0, T1, P,
                                                 1024, 2048, 2048, 2048,
                                                 (size_t)1024 * 2048);
  reduce_part<4><<<1024 * 2048 / 4 / 256, blk, 0, stream>>>(
      P, coact0, 1024 * 2048 / 4, (size_t)1024 * 2048);

  // coact1 = Act1^T @ Act2 -> [2048,2048]; z=2 (Kc=4096)
  gemm_nt_i8<<<dim3(16, 16, 2), blk, 0, stream>>>(T1, T2, P,
                                                  2048, 2048, 4096, 2048,
                                                  (size_t)2048 * 2048);
  reduce_part<2><<<2048 * 2048 / 4 / 256, blk, 0, stream>>>(
      P, coact1, 2048 * 2048 / 4, (size_t)2048 * 2048);

  // coact2 = Act2^T @ Act3 -> [2048,1000]; z=4 (Kc=2048)
  gemm_nt_i8<<<dim3(8, 16, 4), blk, 0, stream>>>(T2, T3, P,
                                                 2048, 1024, 2048, 1000,
                                                 (size_t)2048 * 1000);
  reduce_part<4><<<2048 * 1000 / 4 / 256, blk, 0, stream>>>(
      P, coact2, 2048 * 1000 / 4, (size_t)2048 * 1000);
}